// Round 1
// 858.052 us; speedup vs baseline: 1.4415x; 1.4415x over previous
//
#include <hip/hip_runtime.h>

// GRU: B=256, T=2048, I=10, H=64, fp32 in/out.
// Round-4 theory: VGPR_Count=104 < 126-reg minimum weight footprint => compiler
// rematerialized weight loads inside the t-loop (L2 reload latency = the
// 1140 cyc/step stall; VALUBusy 14.3% == modeled 190 issue cyc / 1330 total).
// Fix: (a) 2-wave K-split halves per-lane W_hh to 48 h2 VGPRs, partials merged
// via __shfl_xor(32) in-wave; (b) x staged to LDS as f16 -> no global/scalar
// loads in the loop; (c) exp2/rcp gates with log2e prescaled into weights;
// (d) asm-pinned weights + waves_per_eu(1,1) so the allocator keeps residency.
// Block = 128 thr (2 waves). Wave w owns units [32w,32w+32); lane j<32 = K-lo,
// j+32 = K-hi of the same unit. h double-buffered in LDS, 1 barrier/step.

#define Bn 256
#define Tn 2048
#define In 10
#define Hn 64

typedef _Float16 h2 __attribute__((ext_vector_type(2)));

__device__ __forceinline__ float dot2(h2 a, h2 b, float c) {
    return __builtin_amdgcn_fdot2(a, b, c, false);
}

extern "C" __global__
__attribute__((amdgpu_flat_work_group_size(128, 128), amdgpu_waves_per_eu(1, 1)))
void gru_kernel(
    const float* __restrict__ noise,  // (B, T, I)
    const float* __restrict__ w_ih,   // (3H, I)
    const float* __restrict__ w_hh,   // (3H, H)
    const float* __restrict__ b_ih,   // (3H)
    const float* __restrict__ b_hh,   // (3H)
    float* __restrict__ out)          // (B, T, H)
{
    const int b   = blockIdx.x;
    const int tid = threadIdx.x;                      // 0..127
    const int u   = ((tid >> 6) << 5) | (tid & 31);   // hidden unit 0..63
    const int kh  = (tid >> 5) & 1;                   // K-half within wave

    __shared__ alignas(16) unsigned short xbuf[Tn * 12];   // x f16, stride 12 (24 B)
    __shared__ alignas(16) unsigned short hbuf[2][Hn];     // h f16, double-buffered

    // ---- stage x (f32 -> f16) into LDS: 16 chunks of 128 rows ----
    {
        const float* xp = noise + (size_t)b * Tn * In;
        for (int c = 0; c < Tn / 128; ++c) {
            const int t = c * 128 + tid;
            const float* px = xp + (size_t)t * In;
            float v[In];
#pragma unroll
            for (int i = 0; i < In; i += 2) {
                float2 f = *(const float2*)(px + i);   // 8B-aligned: t*40+i*4
                v[i] = f.x; v[i + 1] = f.y;
            }
            unsigned int p[5];
#pragma unroll
            for (int i = 0; i < 5; ++i)
                p[i] = __builtin_bit_cast(unsigned int,
                           h2{(_Float16)v[2 * i], (_Float16)v[2 * i + 1]});
            unsigned int* xw = (unsigned int*)(xbuf + t * 12);
            *(uint2*)(xw + 0) = uint2{p[0], p[1]};
            *(uint2*)(xw + 2) = uint2{p[2], p[3]};
            xw[4] = p[4];
        }
        if (tid < Hn) { hbuf[0][tid] = 0; hbuf[1][tid] = 0; }
    }

    // ---- per-lane weights, prescaled for exp2-native gates ----
    const float SR = -1.44269504f;   // -log2(e): sigmoid(u) = rcp(1+exp2(SR*u))
    const float SN =  2.88539008f;   // 2*log2(e): tanh(p) = 1-2*rcp(exp2(SN*p)+1)

    h2 wr[16], wz[16], wn[16];       // this lane's K-half of 3 W_hh rows (48 VGPRs)
    {
        const float* pr = w_hh + (size_t)(0 * Hn + u) * Hn + kh * 32;
        const float* pz = w_hh + (size_t)(1 * Hn + u) * Hn + kh * 32;
        const float* pn = w_hh + (size_t)(2 * Hn + u) * Hn + kh * 32;
#pragma unroll
        for (int k = 0; k < 16; ++k) {
            wr[k] = h2{(_Float16)(SR * pr[2 * k]), (_Float16)(SR * pr[2 * k + 1])};
            wz[k] = h2{(_Float16)(SR * pz[2 * k]), (_Float16)(SR * pz[2 * k + 1])};
            wn[k] = h2{(_Float16)(SN * pn[2 * k]), (_Float16)(SN * pn[2 * k + 1])};
        }
    }
    float wir[In], wiz[In], win[In];  // input-proj rows stay fp32 (30 VGPRs)
#pragma unroll
    for (int i = 0; i < In; ++i) {
        wir[i] = SR * w_ih[(0 * Hn + u) * In + i];
        wiz[i] = SR * w_ih[(1 * Hn + u) * In + i];
        win[i] = SN * w_ih[(2 * Hn + u) * In + i];
    }
    const float brz_r = SR * (b_ih[0 * Hn + u] + b_hh[0 * Hn + u]);
    const float brz_z = SR * (b_ih[1 * Hn + u] + b_hh[1 * Hn + u]);
    const float bi_n  = SN * b_ih[2 * Hn + u];
    // b_hh_n lives inside the K-split sum: add it on the lo-half only.
    const float bh_n0 = ((tid & 63) < 32) ? SN * b_hh[2 * Hn + u] : 0.0f;

    // Pin weights into VGPRs: opaque to remat, allocator must keep them live.
#pragma unroll
    for (int k = 0; k < 16; ++k)
        asm volatile("" : "+v"(wr[k]), "+v"(wz[k]), "+v"(wn[k]));
#pragma unroll
    for (int i = 0; i < In; ++i)
        asm volatile("" : "+v"(wir[i]), "+v"(wiz[i]), "+v"(win[i]));

    float hold = 0.0f;
    float* __restrict__ op = out + (size_t)b * Tn * Hn;

    __syncthreads();

    for (int t = 0; t < Tn; ++t) {
        // x read (uniform LDS broadcast) then h quads: x returns first on the
        // in-order DS pipe, so the proj FMAs overlap the h-read latency tail.
        const unsigned int* xr = (const unsigned int*)(xbuf + t * 12);
        uint2 xa  = *(const uint2*)(xr + 0);
        uint2 xb2 = *(const uint2*)(xr + 2);
        unsigned int xc4 = xr[4];

        const uint4* hq4 = (const uint4*)(&hbuf[t & 1][kh * 32]);
        uint4 q0 = hq4[0], q1 = hq4[1], q2 = hq4[2], q3 = hq4[3];

        float xf[10];
        {
            h2 t0 = __builtin_bit_cast(h2, xa.x),  t1 = __builtin_bit_cast(h2, xa.y);
            h2 t2 = __builtin_bit_cast(h2, xb2.x), t3 = __builtin_bit_cast(h2, xb2.y);
            h2 t4 = __builtin_bit_cast(h2, xc4);
            xf[0] = (float)t0[0]; xf[1] = (float)t0[1];
            xf[2] = (float)t1[0]; xf[3] = (float)t1[1];
            xf[4] = (float)t2[0]; xf[5] = (float)t2[1];
            xf[6] = (float)t3[0]; xf[7] = (float)t3[1];
            xf[8] = (float)t4[0]; xf[9] = (float)t4[1];
        }
        float gr = brz_r, gz = brz_z, gn = bi_n;
#pragma unroll
        for (int i = 0; i < In; ++i) {
            gr = fmaf(wir[i], xf[i], gr);
            gz = fmaf(wiz[i], xf[i], gz);
            gn = fmaf(win[i], xf[i], gn);
        }

        // 48 dot2 in 6 independent chains over this lane's K-half.
        float ar0 = 0.f, ar1 = 0.f, az0 = 0.f, az1 = 0.f, an0 = bh_n0, an1 = 0.f;
#pragma unroll
        for (int q = 0; q < 4; ++q) {
            uint4 uq = (q == 0) ? q0 : (q == 1) ? q1 : (q == 2) ? q2 : q3;
            h2 p0 = __builtin_bit_cast(h2, uq.x);
            h2 p1 = __builtin_bit_cast(h2, uq.y);
            h2 p2 = __builtin_bit_cast(h2, uq.z);
            h2 p3 = __builtin_bit_cast(h2, uq.w);
            const int k = 4 * q;
            ar0 = dot2(wr[k + 0], p0, ar0); az0 = dot2(wz[k + 0], p0, az0); an0 = dot2(wn[k + 0], p0, an0);
            ar1 = dot2(wr[k + 1], p1, ar1); az1 = dot2(wz[k + 1], p1, az1); an1 = dot2(wn[k + 1], p1, an1);
            ar0 = dot2(wr[k + 2], p2, ar0); az0 = dot2(wz[k + 2], p2, az0); an0 = dot2(wn[k + 2], p2, an0);
            ar1 = dot2(wr[k + 3], p3, ar1); az1 = dot2(wz[k + 3], p3, az1); an1 = dot2(wn[k + 3], p3, an1);
        }
        float ar = ar0 + ar1, az = az0 + az1, an = an0 + an1;
        // Merge K-halves: lane j <-> j^32 within the wave; both get the total.
        ar += __shfl_xor(ar, 32);
        az += __shfl_xor(az, 32);
        an += __shfl_xor(an, 32);

        // Gates (prescaled): r = sigmoid, z = sigmoid, n = tanh. Saturation OK
        // (exp2->inf => rcp->0 => r=0 / nn=1; exp2->0 => nn=-1).
        const float r  = __builtin_amdgcn_rcpf(1.0f + __builtin_amdgcn_exp2f(gr + ar));
        const float z  = __builtin_amdgcn_rcpf(1.0f + __builtin_amdgcn_exp2f(gz + az));
        const float pn2 = fmaf(r, an, gn);                 // 2*log2e*(gn + r*an)
        const float e   = __builtin_amdgcn_exp2f(pn2);
        const float nn  = fmaf(-2.0f, __builtin_amdgcn_rcpf(e + 1.0f), 1.0f);
        const float hn  = fmaf(z, hold - nn, nn);          // (1-z)*n + z*h
        hold = hn;

        if ((tid & 63) < 32) {                             // lo-half publishes
            op[(size_t)t * Hn + u] = hn;                   // coalesced 128B/half-wave
            hbuf[(t + 1) & 1][u] =
                __builtin_bit_cast(unsigned short, (_Float16)hn);
        }
        __syncthreads();                                   // cross-wave h visibility
    }
}

extern "C" void kernel_launch(void* const* d_in, const int* in_sizes, int n_in,
                              void* d_out, int out_size, void* d_ws, size_t ws_size,
                              hipStream_t stream) {
    gru_kernel<<<Bn, 128, 0, stream>>>(
        (const float*)d_in[0], (const float*)d_in[1], (const float*)d_in[2],
        (const float*)d_in[3], (const float*)d_in[4], (float*)d_out);
}